// Round 2
// baseline (79.950 us; speedup 1.0000x reference)
//
#include <hip/hip_runtime.h>
#include <hip/hip_bf16.h>

typedef _Float16 f16x8 __attribute__((ext_vector_type(8)));
typedef _Float16 f16x4 __attribute__((ext_vector_type(4)));
typedef float    f32x4 __attribute__((ext_vector_type(4)));

constexpr int BB = 4;
constexpr int CH = 128;
constexpr int PC = 64;
constexpr int NN = 4096;

// ---------------------------------------------------------------------------
// proj_pos: pos = f16(Wp @ pos_bot + bp) -> xbuf [B,N,64], sq = ||x~||^2.
// grid (N/16, B), 4 waves/block; wave w owns output-channel tile w (16 ch).
// 1024 blocks -> ~16 waves/CU (vs 4 in the previous round's fused proj).
// ---------------------------------------------------------------------------
__global__ __launch_bounds__(256) void proj_pos_kernel(
    const float* __restrict__ pos_bot,  // [B,64,N]
    const float* __restrict__ Wp,       // [64,64]
    const float* __restrict__ bp,       // [64]
    _Float16* __restrict__ xbuf,        // [B,N,64]
    float*    __restrict__ sq)          // [B,N]
{
    const int tid  = threadIdx.x;
    const int wid  = tid >> 6;
    const int lane = tid & 63;
    const int l15  = lane & 15;
    const int lg   = lane >> 4;
    const int b    = blockIdx.y;
    const int n    = blockIdx.x * 16 + l15;
    const int mt   = wid;

    f16x8 wf[2], pb[2];
#pragma unroll
    for (int ks = 0; ks < 2; ++ks) {
        const float* wp = Wp + (mt * 16 + l15) * PC + ks * 32 + lg * 8;
        f32x4 w0 = *reinterpret_cast<const f32x4*>(wp);
        f32x4 w1 = *reinterpret_cast<const f32x4*>(wp + 4);
        f16x8 f;
#pragma unroll
        for (int e = 0; e < 4; ++e) { f[e] = (_Float16)w0[e]; f[e + 4] = (_Float16)w1[e]; }
        wf[ks] = f;
        f16x8 g;
#pragma unroll
        for (int e = 0; e < 8; ++e) {
            const int c = ks * 32 + lg * 8 + e;
            g[e] = (_Float16)pos_bot[((size_t)(b * PC + c)) * NN + n];
        }
        pb[ks] = g;
    }

    f32x4 acc = {0.f, 0.f, 0.f, 0.f};
    acc = __builtin_amdgcn_mfma_f32_16x16x32_f16(wf[0], pb[0], acc, 0, 0, 0);
    acc = __builtin_amdgcn_mfma_f32_16x16x32_f16(wf[1], pb[1], acc, 0, 0, 0);

    float partial = 0.f;
    f16x4 h4;
#pragma unroll
    for (int r = 0; r < 4; ++r) {
        const int o = mt * 16 + lg * 4 + r;
        const float v = acc[r] + bp[o];
        const _Float16 h = (_Float16)v;
        h4[r] = h;
        const float hf = (float)h;
        partial = fmaf(hf, hf, partial);
    }
    *reinterpret_cast<f16x4*>(xbuf + ((size_t)(b * NN + n)) * PC + mt * 16 + lg * 4) = h4;

    partial += __shfl_xor(partial, 16);
    partial += __shfl_xor(partial, 32);
    __shared__ float psum[4][16];
    if (lane < 16) psum[wid][l15] = partial;
    __syncthreads();
    if (tid < 16)
        sq[b * NN + blockIdx.x * 16 + tid] =
            psum[0][tid] + psum[1][tid] + psum[2][tid] + psum[3][tid];
}

// ---------------------------------------------------------------------------
// gram (+ hidden value-projection blocks at blockIdx.z == BB).
// Gram: block tile 128x128, 4 waves (2x2), wave tile 64x64.
//   MFMA operands SWAPPED vs round 1 (gram is symmetric, i<->j free) so each
//   lane holds 4 consecutive-j values -> global_store_dwordx4 epilogue.
//   kv = exp2(min(ti + tj + m2bs*dot, 0)), ti/tj = bs*sq (1 fma+1 min+1 exp2).
// Value-proj blocks: 1024 blocks ride along with zero serial cost; wave w
//   computes output-channel tiles {w, w+4} for 16 positions.
// ---------------------------------------------------------------------------
__global__ __launch_bounds__(256) void gram_kernel(
    const _Float16* __restrict__ xbuf,  // [B,N,64]
    const float*    __restrict__ sq,    // [B,N]
    const float*    __restrict__ beta,  // [1]
    float*          __restrict__ out,   // [B,N,N]
    const float*    __restrict__ corr,  // [B,128,N]
    const float*    __restrict__ Wv,    // [128,128]
    const float*    __restrict__ bv,    // [128]
    float*          __restrict__ eqF)   // [B,N,128]
{
    const int tid  = threadIdx.x;
    const int wid  = tid >> 6;
    const int lane = tid & 63;
    const int l15  = lane & 15;
    const int lg   = lane >> 4;

    if (blockIdx.z == BB) {
        // ---- value projection ----
        const int blk = blockIdx.y * 32 + blockIdx.x;   // 0..1023
        const int b   = blk >> 8;
        const int n   = (blk & 255) * 16 + l15;

        f16x8 cb[4];
#pragma unroll
        for (int ks = 0; ks < 4; ++ks) {
            f16x8 g;
#pragma unroll
            for (int e = 0; e < 8; ++e) {
                const int c = ks * 32 + lg * 8 + e;
                g[e] = (_Float16)corr[((size_t)(b * CH + c)) * NN + n];
            }
            cb[ks] = g;
        }
#pragma unroll
        for (int half = 0; half < 2; ++half) {
            const int ot = wid + half * 4;              // 0..7
            f32x4 acc = {0.f, 0.f, 0.f, 0.f};
#pragma unroll
            for (int ks = 0; ks < 4; ++ks) {
                const float* wv = Wv + (ot * 16 + l15) * CH + ks * 32 + lg * 8;
                f32x4 w0 = *reinterpret_cast<const f32x4*>(wv);
                f32x4 w1 = *reinterpret_cast<const f32x4*>(wv + 4);
                f16x8 f;
#pragma unroll
                for (int e = 0; e < 4; ++e) { f[e] = (_Float16)w0[e]; f[e + 4] = (_Float16)w1[e]; }
                acc = __builtin_amdgcn_mfma_f32_16x16x32_f16(f, cb[ks], acc, 0, 0, 0);
            }
            f32x4 o4;
#pragma unroll
            for (int r = 0; r < 4; ++r) o4[r] = acc[r] + bv[ot * 16 + lg * 4 + r];
            *reinterpret_cast<f32x4*>(eqF + ((size_t)(b * NN + n)) * CH + ot * 16 + lg * 4) = o4;
        }
        return;
    }

    // ---- gram + RBF ----
    const int wr = wid >> 1;
    const int wc = wid & 1;
    const int b  = blockIdx.z;
    const int ib = blockIdx.x * 128 + wr * 64;
    const int jb = blockIdx.y * 128 + wc * 64;

    const _Float16* xb = xbuf + (size_t)b * NN * PC;
    const f32x4 zero = {0.f, 0.f, 0.f, 0.f};

    f16x8 af[4][2], bf[4][2];
#pragma unroll
    for (int t = 0; t < 4; ++t)
#pragma unroll
        for (int ks = 0; ks < 2; ++ks) {
            af[t][ks] = *reinterpret_cast<const f16x8*>(
                xb + (size_t)(ib + t * 16 + l15) * PC + ks * 32 + lg * 8);
            bf[t][ks] = *reinterpret_cast<const f16x8*>(
                xb + (size_t)(jb + t * 16 + l15) * PC + ks * 32 + lg * 8);
        }

    f32x4 acc[4][4];
#pragma unroll
    for (int it = 0; it < 4; ++it)
#pragma unroll
        for (int jt = 0; jt < 4; ++jt) acc[it][jt] = zero;

    // Swapped operands: D[row = j-local][col = i-local]; lane (l15, lg) reg r
    // holds dot(x_{ib+it*16+l15}, x_{jb+jt*16+lg*4+r}) -> 4 consecutive j.
#pragma unroll
    for (int ks = 0; ks < 2; ++ks)
#pragma unroll
        for (int it = 0; it < 4; ++it)
#pragma unroll
            for (int jt = 0; jt < 4; ++jt)
                acc[it][jt] = __builtin_amdgcn_mfma_f32_16x16x32_f16(
                    bf[jt][ks], af[it][ks], acc[it][jt], 0, 0, 0);

    const float* sqb = sq + (size_t)b * NN;
    const float bs   = -beta[0] * 1.44269504088896f;   // exp(-beta*d2)=exp2(bs*d2)
    const float m2bs = -2.f * bs;

    f32x4 tj[4];
#pragma unroll
    for (int jt = 0; jt < 4; ++jt) {
        f32x4 s = *reinterpret_cast<const f32x4*>(sqb + jb + jt * 16 + lg * 4);
        tj[jt] = s * bs;
    }

#pragma unroll
    for (int it = 0; it < 4; ++it) {
        const int i   = ib + it * 16 + l15;
        const float ti = bs * sqb[i];
        float* orow = out + ((size_t)(b * NN + i)) * NN;
#pragma unroll
        for (int jt = 0; jt < 4; ++jt) {
            f32x4 v;
#pragma unroll
            for (int r = 0; r < 4; ++r) {
                float arg = fmaf(m2bs, acc[it][jt][r], ti + tj[jt][r]);
                arg = fminf(arg, 0.f);                 // == bs * max(d2, 0)
                v[r] = __builtin_amdgcn_exp2f(arg);
            }
            *reinterpret_cast<f32x4*>(orow + jb + jt * 16 + lg * 4) = v;
        }
    }
}

extern "C" void kernel_launch(void* const* d_in, const int* in_sizes, int n_in,
                              void* d_out, int out_size, void* d_ws, size_t ws_size,
                              hipStream_t stream) {
    const float* pos_bot = (const float*)d_in[0];
    const float* corr    = (const float*)d_in[1];
    const float* Wp      = (const float*)d_in[2];
    const float* bp      = (const float*)d_in[3];
    const float* Wv      = (const float*)d_in[4];
    const float* bv      = (const float*)d_in[5];
    const float* beta    = (const float*)d_in[6];

    float* out = (float*)d_out;                       // kernel [B,N,N]
    float* eqF = out + (size_t)BB * NN * NN;          // equation_F [B,N,128]

    _Float16* xbuf = (_Float16*)d_ws;                 // 2 MB
    float* sq = (float*)((char*)d_ws + (size_t)BB * NN * PC * sizeof(_Float16));

    proj_pos_kernel<<<dim3(NN / 16, BB), 256, 0, stream>>>(pos_bot, Wp, bp, xbuf, sq);

    // z == BB blocks do the value projection, hidden under gram's BW stream.
    gram_kernel<<<dim3(NN / 128, NN / 128, BB + 1), 256, 0, stream>>>(
        xbuf, sq, beta, out, corr, Wv, bv, eqF);
}

// Round 3
// 78.867 us; speedup vs baseline: 1.0137x; 1.0137x over previous
//
#include <hip/hip_runtime.h>
#include <hip/hip_bf16.h>

typedef _Float16 f16x8 __attribute__((ext_vector_type(8)));
typedef _Float16 f16x4 __attribute__((ext_vector_type(4)));
typedef float    f32x4 __attribute__((ext_vector_type(4)));

constexpr int BB = 4;
constexpr int CH = 128;
constexpr int PC = 64;
constexpr int NN = 4096;

// ---------------------------------------------------------------------------
// proj_pos: x~ = f16(Wp @ pos_bot + bp) -> xbuf [B,N,64], sq = ||x~||^2.
// grid (N/16, B), 4 waves/block; wave w owns output-channel tile w.
// ---------------------------------------------------------------------------
__global__ __launch_bounds__(256) void proj_pos_kernel(
    const float* __restrict__ pos_bot,  // [B,64,N]
    const float* __restrict__ Wp,       // [64,64]
    const float* __restrict__ bp,       // [64]
    _Float16* __restrict__ xbuf,        // [B,N,64]
    float*    __restrict__ sq)          // [B,N]
{
    const int tid  = threadIdx.x;
    const int wid  = tid >> 6;
    const int lane = tid & 63;
    const int l15  = lane & 15;
    const int lg   = lane >> 4;
    const int b    = blockIdx.y;
    const int n    = blockIdx.x * 16 + l15;
    const int mt   = wid;

    f16x8 wf[2], pb[2];
#pragma unroll
    for (int ks = 0; ks < 2; ++ks) {
        const float* wp = Wp + (mt * 16 + l15) * PC + ks * 32 + lg * 8;
        f32x4 w0 = *reinterpret_cast<const f32x4*>(wp);
        f32x4 w1 = *reinterpret_cast<const f32x4*>(wp + 4);
        f16x8 f;
#pragma unroll
        for (int e = 0; e < 4; ++e) { f[e] = (_Float16)w0[e]; f[e + 4] = (_Float16)w1[e]; }
        wf[ks] = f;
        f16x8 g;
#pragma unroll
        for (int e = 0; e < 8; ++e) {
            const int c = ks * 32 + lg * 8 + e;
            g[e] = (_Float16)pos_bot[((size_t)(b * PC + c)) * NN + n];
        }
        pb[ks] = g;
    }

    f32x4 acc = {0.f, 0.f, 0.f, 0.f};
    acc = __builtin_amdgcn_mfma_f32_16x16x32_f16(wf[0], pb[0], acc, 0, 0, 0);
    acc = __builtin_amdgcn_mfma_f32_16x16x32_f16(wf[1], pb[1], acc, 0, 0, 0);

    float partial = 0.f;
    f16x4 h4;
#pragma unroll
    for (int r = 0; r < 4; ++r) {
        const int o = mt * 16 + lg * 4 + r;
        const float v = acc[r] + bp[o];
        const _Float16 h = (_Float16)v;
        h4[r] = h;
        const float hf = (float)h;
        partial = fmaf(hf, hf, partial);
    }
    *reinterpret_cast<f16x4*>(xbuf + ((size_t)(b * NN + n)) * PC + mt * 16 + lg * 4) = h4;

    partial += __shfl_xor(partial, 16);
    partial += __shfl_xor(partial, 32);
    __shared__ float psum[4][16];
    if (lane < 16) psum[wid][l15] = partial;
    __syncthreads();
    if (tid < 16)
        sq[b * NN + blockIdx.x * 16 + tid] =
            psum[0][tid] + psum[1][tid] + psum[2][tid] + psum[3][tid];
}

// ---------------------------------------------------------------------------
// proj_val: equation_F = Wv @ corr + bv. grid (N/16, B), 4 waves; wave w does
// output-channel tiles {w, w+4}. 1024 blocks -> latency fully parallel.
// ---------------------------------------------------------------------------
__global__ __launch_bounds__(256) void proj_val_kernel(
    const float* __restrict__ corr,  // [B,128,N]
    const float* __restrict__ Wv,    // [128,128]
    const float* __restrict__ bv,    // [128]
    float*       __restrict__ eqF)   // [B,N,128]
{
    const int tid  = threadIdx.x;
    const int wid  = tid >> 6;
    const int lane = tid & 63;
    const int l15  = lane & 15;
    const int lg   = lane >> 4;
    const int b    = blockIdx.y;
    const int n    = blockIdx.x * 16 + l15;

    f16x8 cb[4];
#pragma unroll
    for (int ks = 0; ks < 4; ++ks) {
        f16x8 g;
#pragma unroll
        for (int e = 0; e < 8; ++e) {
            const int c = ks * 32 + lg * 8 + e;
            g[e] = (_Float16)corr[((size_t)(b * CH + c)) * NN + n];
        }
        cb[ks] = g;
    }
#pragma unroll
    for (int half = 0; half < 2; ++half) {
        const int ot = wid + half * 4;   // 0..7
        f32x4 acc = {0.f, 0.f, 0.f, 0.f};
#pragma unroll
        for (int ks = 0; ks < 4; ++ks) {
            const float* wv = Wv + (ot * 16 + l15) * CH + ks * 32 + lg * 8;
            f32x4 w0 = *reinterpret_cast<const f32x4*>(wv);
            f32x4 w1 = *reinterpret_cast<const f32x4*>(wv + 4);
            f16x8 f;
#pragma unroll
            for (int e = 0; e < 4; ++e) { f[e] = (_Float16)w0[e]; f[e + 4] = (_Float16)w1[e]; }
            acc = __builtin_amdgcn_mfma_f32_16x16x32_f16(f, cb[ks], acc, 0, 0, 0);
        }
        f32x4 o4;
#pragma unroll
        for (int r = 0; r < 4; ++r) o4[r] = acc[r] + bv[ot * 16 + lg * 4 + r];
        *reinterpret_cast<f32x4*>(eqF + ((size_t)(b * NN + n)) * CH + ot * 16 + lg * 4) = o4;
    }
}

// ---------------------------------------------------------------------------
// gram: row-strip tiling for sequential writes.
// Block = 512 threads = 8 waves. Block tile = 32 rows x 4096 cols (512 KB of
// output, FULLY covering 32 contiguous rows). Wave w sweeps cols w*512..+511
// left->right in 16-col steps: transient acc (2 f32x4), B-fragments stream
// from L2 (xbuf 512 KB/batch resident), stores are monotone sequential
// streams like the fill kernel. Software-pipelined B-load 1 step ahead.
// grid (N/32, B) = 512 blocks = 2/CU, 16 waves/CU.
// ---------------------------------------------------------------------------
__global__ __launch_bounds__(512) void gram_kernel(
    const _Float16* __restrict__ xbuf,  // [B,N,64]
    const float*    __restrict__ sq,    // [B,N]
    const float*    __restrict__ beta,  // [1]
    float*          __restrict__ out)   // [B,N,N]
{
    const int tid  = threadIdx.x;
    const int wid  = tid >> 6;          // 0..7
    const int lane = tid & 63;
    const int l15  = lane & 15;
    const int lg   = lane >> 4;
    const int b    = blockIdx.y;
    const int rb   = blockIdx.x * 32;   // row strip base

    const _Float16* xb  = xbuf + (size_t)b * NN * PC;
    const float*    sqb = sq + (size_t)b * NN;

    // A fragments: rows rb + it*16 + l15, held for the whole sweep.
    f16x8 af[2][2];
#pragma unroll
    for (int it = 0; it < 2; ++it)
#pragma unroll
        for (int ks = 0; ks < 2; ++ks)
            af[it][ks] = *reinterpret_cast<const f16x8*>(
                xb + (size_t)(rb + it * 16 + l15) * PC + ks * 32 + lg * 8);

    const float bs   = -beta[0] * 1.44269504088896f;  // exp(-b*d2)=exp2(bs*d2)
    const float m2bs = -2.f * bs;

    float ti[2][4];
#pragma unroll
    for (int it = 0; it < 2; ++it)
#pragma unroll
        for (int r = 0; r < 4; ++r)
            ti[it][r] = bs * sqb[rb + it * 16 + lg * 4 + r];

    const int jbase = wid * 512;

    f16x8 b0, b1, n0, n1;
    float tj, ntj;
    {
        const int j = jbase;
        b0 = *reinterpret_cast<const f16x8*>(xb + (size_t)(j + l15) * PC + lg * 8);
        b1 = *reinterpret_cast<const f16x8*>(xb + (size_t)(j + l15) * PC + 32 + lg * 8);
        tj = bs * sqb[j + l15];
    }

    for (int jt = 0; jt < 32; ++jt) {
        const int jn = jbase + (jt < 31 ? jt + 1 : 31) * 16;
        n0 = *reinterpret_cast<const f16x8*>(xb + (size_t)(jn + l15) * PC + lg * 8);
        n1 = *reinterpret_cast<const f16x8*>(xb + (size_t)(jn + l15) * PC + 32 + lg * 8);
        ntj = bs * sqb[jn + l15];

        f32x4 acc0 = {0.f, 0.f, 0.f, 0.f};
        f32x4 acc1 = {0.f, 0.f, 0.f, 0.f};
        acc0 = __builtin_amdgcn_mfma_f32_16x16x32_f16(af[0][0], b0, acc0, 0, 0, 0);
        acc0 = __builtin_amdgcn_mfma_f32_16x16x32_f16(af[0][1], b1, acc0, 0, 0, 0);
        acc1 = __builtin_amdgcn_mfma_f32_16x16x32_f16(af[1][0], b0, acc1, 0, 0, 0);
        acc1 = __builtin_amdgcn_mfma_f32_16x16x32_f16(af[1][1], b1, acc1, 0, 0, 0);

        const int j = jbase + jt * 16 + l15;
#pragma unroll
        for (int r = 0; r < 4; ++r) {
            float a0 = fminf(fmaf(m2bs, acc0[r], ti[0][r] + tj), 0.f);
            out[((size_t)(b * NN + rb + lg * 4 + r)) * NN + j] =
                __builtin_amdgcn_exp2f(a0);
            float a1 = fminf(fmaf(m2bs, acc1[r], ti[1][r] + tj), 0.f);
            out[((size_t)(b * NN + rb + 16 + lg * 4 + r)) * NN + j] =
                __builtin_amdgcn_exp2f(a1);
        }

        b0 = n0; b1 = n1; tj = ntj;
    }
}

extern "C" void kernel_launch(void* const* d_in, const int* in_sizes, int n_in,
                              void* d_out, int out_size, void* d_ws, size_t ws_size,
                              hipStream_t stream) {
    const float* pos_bot = (const float*)d_in[0];
    const float* corr    = (const float*)d_in[1];
    const float* Wp      = (const float*)d_in[2];
    const float* bp      = (const float*)d_in[3];
    const float* Wv      = (const float*)d_in[4];
    const float* bv      = (const float*)d_in[5];
    const float* beta    = (const float*)d_in[6];

    float* out = (float*)d_out;                       // kernel [B,N,N]
    float* eqF = out + (size_t)BB * NN * NN;          // equation_F [B,N,128]

    _Float16* xbuf = (_Float16*)d_ws;                 // 2 MB
    float* sq = (float*)((char*)d_ws + (size_t)BB * NN * PC * sizeof(_Float16));

    proj_pos_kernel<<<dim3(NN / 16, BB), 256, 0, stream>>>(pos_bot, Wp, bp, xbuf, sq);
    proj_val_kernel<<<dim3(NN / 16, BB), 256, 0, stream>>>(corr, Wv, bv, eqF);
    gram_kernel<<<dim3(NN / 32, BB), 512, 0, stream>>>(xbuf, sq, beta, out);
}

// Round 4
// 76.908 us; speedup vs baseline: 1.0396x; 1.0255x over previous
//
#include <hip/hip_runtime.h>
#include <hip/hip_bf16.h>

typedef _Float16 f16x8 __attribute__((ext_vector_type(8)));
typedef _Float16 f16x4 __attribute__((ext_vector_type(4)));
typedef float    f32x4 __attribute__((ext_vector_type(4)));

constexpr int BB = 4;
constexpr int CH = 128;
constexpr int PC = 64;
constexpr int NN = 4096;

// ---------------------------------------------------------------------------
// proj_pos: x~ = f16(Wp @ pos_bot + bp) -> xbuf [B,N,64], sq = ||x~||^2.
// grid (N/16, B) = 1024 blocks, 4 waves/block; wave w owns channel tile w.
// ---------------------------------------------------------------------------
__global__ __launch_bounds__(256) void proj_pos_kernel(
    const float* __restrict__ pos_bot,  // [B,64,N]
    const float* __restrict__ Wp,       // [64,64]
    const float* __restrict__ bp,       // [64]
    _Float16* __restrict__ xbuf,        // [B,N,64]
    float*    __restrict__ sq)          // [B,N]
{
    const int tid  = threadIdx.x;
    const int wid  = tid >> 6;
    const int lane = tid & 63;
    const int l15  = lane & 15;
    const int lg   = lane >> 4;
    const int b    = blockIdx.y;
    const int n    = blockIdx.x * 16 + l15;
    const int mt   = wid;

    f16x8 wf[2], pb[2];
#pragma unroll
    for (int ks = 0; ks < 2; ++ks) {
        const float* wp = Wp + (mt * 16 + l15) * PC + ks * 32 + lg * 8;
        f32x4 w0 = *reinterpret_cast<const f32x4*>(wp);
        f32x4 w1 = *reinterpret_cast<const f32x4*>(wp + 4);
        f16x8 f;
#pragma unroll
        for (int e = 0; e < 4; ++e) { f[e] = (_Float16)w0[e]; f[e + 4] = (_Float16)w1[e]; }
        wf[ks] = f;
        f16x8 g;
#pragma unroll
        for (int e = 0; e < 8; ++e) {
            const int c = ks * 32 + lg * 8 + e;
            g[e] = (_Float16)pos_bot[((size_t)(b * PC + c)) * NN + n];
        }
        pb[ks] = g;
    }

    f32x4 acc = {0.f, 0.f, 0.f, 0.f};
    acc = __builtin_amdgcn_mfma_f32_16x16x32_f16(wf[0], pb[0], acc, 0, 0, 0);
    acc = __builtin_amdgcn_mfma_f32_16x16x32_f16(wf[1], pb[1], acc, 0, 0, 0);

    float partial = 0.f;
    f16x4 h4;
#pragma unroll
    for (int r = 0; r < 4; ++r) {
        const int o = mt * 16 + lg * 4 + r;
        const float v = acc[r] + bp[o];
        const _Float16 h = (_Float16)v;
        h4[r] = h;
        const float hf = (float)h;
        partial = fmaf(hf, hf, partial);
    }
    *reinterpret_cast<f16x4*>(xbuf + ((size_t)(b * NN + n)) * PC + mt * 16 + lg * 4) = h4;

    partial += __shfl_xor(partial, 16);
    partial += __shfl_xor(partial, 32);
    __shared__ float psum[4][16];
    if (lane < 16) psum[wid][l15] = partial;
    __syncthreads();
    if (tid < 16)
        sq[b * NN + blockIdx.x * 16 + tid] =
            psum[0][tid] + psum[1][tid] + psum[2][tid] + psum[3][tid];
}

// ---------------------------------------------------------------------------
// gram_val: flat grid of 1024 value-proj blocks (FIRST -> dispatched first,
// fully hidden under the gram stream; independent of xbuf) + 4096 gram blocks.
//
// Gram (r1-proven tiled form): block tile 128x128, 4 waves (2x2), wave 64x64.
// Swapped MFMA operands (gram symmetric) so each lane holds 4 consecutive j
// -> global_store_dwordx4. kv = exp2(min(ti + tj + m2bs*dot, 0)).
// ---------------------------------------------------------------------------
__global__ __launch_bounds__(256) void gram_val_kernel(
    const _Float16* __restrict__ xbuf,  // [B,N,64]
    const float*    __restrict__ sq,    // [B,N]
    const float*    __restrict__ beta,  // [1]
    float*          __restrict__ out,   // [B,N,N]
    const float*    __restrict__ corr,  // [B,128,N]
    const float*    __restrict__ Wv,    // [128,128]
    const float*    __restrict__ bv,    // [128]
    float*          __restrict__ eqF)   // [B,N,128]
{
    const int bid  = blockIdx.x;
    const int tid  = threadIdx.x;
    const int wid  = tid >> 6;
    const int lane = tid & 63;
    const int l15  = lane & 15;
    const int lg   = lane >> 4;

    if (bid < 1024) {
        // ---- value projection: eqF = Wv @ corr + bv ----
        const int b = bid >> 8;
        const int n = (bid & 255) * 16 + l15;

        f16x8 cb[4];
#pragma unroll
        for (int ks = 0; ks < 4; ++ks) {
            f16x8 g;
#pragma unroll
            for (int e = 0; e < 8; ++e) {
                const int c = ks * 32 + lg * 8 + e;
                g[e] = (_Float16)corr[((size_t)(b * CH + c)) * NN + n];
            }
            cb[ks] = g;
        }
#pragma unroll
        for (int half = 0; half < 2; ++half) {
            const int ot = wid + half * 4;   // 0..7
            f32x4 acc = {0.f, 0.f, 0.f, 0.f};
#pragma unroll
            for (int ks = 0; ks < 4; ++ks) {
                const float* wv = Wv + (ot * 16 + l15) * CH + ks * 32 + lg * 8;
                f32x4 w0 = *reinterpret_cast<const f32x4*>(wv);
                f32x4 w1 = *reinterpret_cast<const f32x4*>(wv + 4);
                f16x8 f;
#pragma unroll
                for (int e = 0; e < 4; ++e) { f[e] = (_Float16)w0[e]; f[e + 4] = (_Float16)w1[e]; }
                acc = __builtin_amdgcn_mfma_f32_16x16x32_f16(f, cb[ks], acc, 0, 0, 0);
            }
            f32x4 o4;
#pragma unroll
            for (int r = 0; r < 4; ++r) o4[r] = acc[r] + bv[ot * 16 + lg * 4 + r];
            *reinterpret_cast<f32x4*>(eqF + ((size_t)(b * NN + n)) * CH + ot * 16 + lg * 4) = o4;
        }
        return;
    }

    // ---- gram + RBF ----
    const int g   = bid - 1024;
    const int b   = g >> 10;
    const int rem = g & 1023;
    const int wr  = wid >> 1;
    const int wc  = wid & 1;
    const int ib  = (rem & 31) * 128 + wr * 64;
    const int jb  = (rem >> 5) * 128 + wc * 64;

    const _Float16* xb = xbuf + (size_t)b * NN * PC;
    const f32x4 zero = {0.f, 0.f, 0.f, 0.f};

    f16x8 af[4][2], bf[4][2];
#pragma unroll
    for (int t = 0; t < 4; ++t)
#pragma unroll
        for (int ks = 0; ks < 2; ++ks) {
            af[t][ks] = *reinterpret_cast<const f16x8*>(
                xb + (size_t)(ib + t * 16 + l15) * PC + ks * 32 + lg * 8);
            bf[t][ks] = *reinterpret_cast<const f16x8*>(
                xb + (size_t)(jb + t * 16 + l15) * PC + ks * 32 + lg * 8);
        }

    f32x4 acc[4][4];
#pragma unroll
    for (int it = 0; it < 4; ++it)
#pragma unroll
        for (int jt = 0; jt < 4; ++jt) acc[it][jt] = zero;

    // Swapped operands: lane (l15 = i-local); regs r -> 4 consecutive j.
#pragma unroll
    for (int ks = 0; ks < 2; ++ks)
#pragma unroll
        for (int it = 0; it < 4; ++it)
#pragma unroll
            for (int jt = 0; jt < 4; ++jt)
                acc[it][jt] = __builtin_amdgcn_mfma_f32_16x16x32_f16(
                    bf[jt][ks], af[it][ks], acc[it][jt], 0, 0, 0);

    const float* sqb = sq + (size_t)b * NN;
    const float bs   = -beta[0] * 1.44269504088896f;  // exp(-b*d2)=exp2(bs*d2)
    const float m2bs = -2.f * bs;

    f32x4 tj[4];
#pragma unroll
    for (int jt = 0; jt < 4; ++jt) {
        f32x4 s = *reinterpret_cast<const f32x4*>(sqb + jb + jt * 16 + lg * 4);
        tj[jt] = s * bs;
    }

#pragma unroll
    for (int it = 0; it < 4; ++it) {
        const int i    = ib + it * 16 + l15;
        const float ti = bs * sqb[i];
        float* orow = out + ((size_t)(b * NN + i)) * NN;
#pragma unroll
        for (int jt = 0; jt < 4; ++jt) {
            f32x4 v;
#pragma unroll
            for (int r = 0; r < 4; ++r) {
                float arg = fmaf(m2bs, acc[it][jt][r], ti + tj[jt][r]);
                arg = fminf(arg, 0.f);
                v[r] = __builtin_amdgcn_exp2f(arg);
            }
            *reinterpret_cast<f32x4*>(orow + jb + jt * 16 + lg * 4) = v;
        }
    }
}

extern "C" void kernel_launch(void* const* d_in, const int* in_sizes, int n_in,
                              void* d_out, int out_size, void* d_ws, size_t ws_size,
                              hipStream_t stream) {
    const float* pos_bot = (const float*)d_in[0];
    const float* corr    = (const float*)d_in[1];
    const float* Wp      = (const float*)d_in[2];
    const float* bp      = (const float*)d_in[3];
    const float* Wv      = (const float*)d_in[4];
    const float* bv      = (const float*)d_in[5];
    const float* beta    = (const float*)d_in[6];

    float* out = (float*)d_out;                       // kernel [B,N,N]
    float* eqF = out + (size_t)BB * NN * NN;          // equation_F [B,N,128]

    _Float16* xbuf = (_Float16*)d_ws;                 // 2 MB
    float* sq = (float*)((char*)d_ws + (size_t)BB * NN * PC * sizeof(_Float16));

    proj_pos_kernel<<<dim3(NN / 16, BB), 256, 0, stream>>>(pos_bot, Wp, bp, xbuf, sq);

    // 1024 val blocks first (hidden under gram), then 4096 gram blocks.
    gram_val_kernel<<<dim3(1024 + 4096), 256, 0, stream>>>(
        xbuf, sq, beta, out, corr, Wv, bv, eqF);
}

// Round 5
// 72.047 us; speedup vs baseline: 1.1097x; 1.0675x over previous
//
#include <hip/hip_runtime.h>
#include <hip/hip_bf16.h>

typedef _Float16 f16x8 __attribute__((ext_vector_type(8)));
typedef _Float16 f16x4 __attribute__((ext_vector_type(4)));
typedef float    f32x4 __attribute__((ext_vector_type(4)));

constexpr int BB = 4;
constexpr int CH = 128;
constexpr int PC = 64;
constexpr int NN = 4096;

// ---------------------------------------------------------------------------
// proj: one launch, grid (N/16, 2*B). role = y>>2 (0: pos-projection + sq,
// 1: value-projection). Both bodies verified in rounds 3/4.
// ---------------------------------------------------------------------------
__global__ __launch_bounds__(256) void proj_kernel(
    const float* __restrict__ pos_bot,  // [B,64,N]
    const float* __restrict__ corr,     // [B,128,N]
    const float* __restrict__ Wp,       // [64,64]
    const float* __restrict__ bp,       // [64]
    const float* __restrict__ Wv,       // [128,128]
    const float* __restrict__ bv,       // [128]
    _Float16* __restrict__ xbuf,        // [B,N,64]
    float*    __restrict__ sq,          // [B,N]
    float*    __restrict__ eqF)         // [B,N,128]
{
    const int tid  = threadIdx.x;
    const int wid  = tid >> 6;
    const int lane = tid & 63;
    const int l15  = lane & 15;
    const int lg   = lane >> 4;
    const int b    = blockIdx.y & 3;
    const int n    = blockIdx.x * 16 + l15;

    if ((blockIdx.y >> 2) == 0) {
        // ---- pos projection: x~ = f16(Wp @ pos_bot + bp), sq = ||x~||^2 ----
        const int mt = wid;
        f16x8 wf[2], pb[2];
#pragma unroll
        for (int ks = 0; ks < 2; ++ks) {
            const float* wp = Wp + (mt * 16 + l15) * PC + ks * 32 + lg * 8;
            f32x4 w0 = *reinterpret_cast<const f32x4*>(wp);
            f32x4 w1 = *reinterpret_cast<const f32x4*>(wp + 4);
            f16x8 f;
#pragma unroll
            for (int e = 0; e < 4; ++e) { f[e] = (_Float16)w0[e]; f[e + 4] = (_Float16)w1[e]; }
            wf[ks] = f;
            f16x8 g;
#pragma unroll
            for (int e = 0; e < 8; ++e) {
                const int c = ks * 32 + lg * 8 + e;
                g[e] = (_Float16)pos_bot[((size_t)(b * PC + c)) * NN + n];
            }
            pb[ks] = g;
        }

        f32x4 acc = {0.f, 0.f, 0.f, 0.f};
        acc = __builtin_amdgcn_mfma_f32_16x16x32_f16(wf[0], pb[0], acc, 0, 0, 0);
        acc = __builtin_amdgcn_mfma_f32_16x16x32_f16(wf[1], pb[1], acc, 0, 0, 0);

        float partial = 0.f;
        f16x4 h4;
#pragma unroll
        for (int r = 0; r < 4; ++r) {
            const int o = mt * 16 + lg * 4 + r;
            const float v = acc[r] + bp[o];
            const _Float16 h = (_Float16)v;
            h4[r] = h;
            const float hf = (float)h;
            partial = fmaf(hf, hf, partial);
        }
        *reinterpret_cast<f16x4*>(xbuf + ((size_t)(b * NN + n)) * PC + mt * 16 + lg * 4) = h4;

        partial += __shfl_xor(partial, 16);
        partial += __shfl_xor(partial, 32);
        __shared__ float psum[4][16];
        if (lane < 16) psum[wid][l15] = partial;
        __syncthreads();
        if (tid < 16)
            sq[b * NN + blockIdx.x * 16 + tid] =
                psum[0][tid] + psum[1][tid] + psum[2][tid] + psum[3][tid];
        return;
    }

    // ---- value projection: eqF = Wv @ corr + bv ----
    f16x8 cb[4];
#pragma unroll
    for (int ks = 0; ks < 4; ++ks) {
        f16x8 g;
#pragma unroll
        for (int e = 0; e < 8; ++e) {
            const int c = ks * 32 + lg * 8 + e;
            g[e] = (_Float16)corr[((size_t)(b * CH + c)) * NN + n];
        }
        cb[ks] = g;
    }
#pragma unroll
    for (int half = 0; half < 2; ++half) {
        const int ot = wid + half * 4;   // 0..7
        f32x4 acc = {0.f, 0.f, 0.f, 0.f};
#pragma unroll
        for (int ks = 0; ks < 4; ++ks) {
            const float* wv = Wv + (ot * 16 + l15) * CH + ks * 32 + lg * 8;
            f32x4 w0 = *reinterpret_cast<const f32x4*>(wv);
            f32x4 w1 = *reinterpret_cast<const f32x4*>(wv + 4);
            f16x8 f;
#pragma unroll
            for (int e = 0; e < 4; ++e) { f[e] = (_Float16)w0[e]; f[e + 4] = (_Float16)w1[e]; }
            acc = __builtin_amdgcn_mfma_f32_16x16x32_f16(f, cb[ks], acc, 0, 0, 0);
        }
        f32x4 o4;
#pragma unroll
        for (int r = 0; r < 4; ++r) o4[r] = acc[r] + bv[ot * 16 + lg * 4 + r];
        *reinterpret_cast<f32x4*>(eqF + ((size_t)(b * NN + n)) * CH + ot * 16 + lg * 4) = o4;
    }
}

// ---------------------------------------------------------------------------
// gram: MFMA tiles + fill-style stores via LDS transpose.
// Block = 256 thr (4 waves), tile 64 i x 512 j; wave w owns j in [w*128,+128).
// Per 16-row slice: 16 MFMAs -> exp2 in regs -> stage [16][516] f32 in LDS
// (pad 4: 2-way bank alias, free) -> copy-out where each wave-instruction
// stores 1 KB CONTIGUOUS within a single row (the fill-kernel pattern),
// replacing the old 16-rows-x-64B scatter.
// grid (N/512, N/64, B) = 2048 blocks; ~150 VGPR, 33 KB LDS -> ~3 blocks/CU.
// MFMA layout (r1-verified): acc=mfma(af,bf): i = lg*4+r, j = l15.
// ---------------------------------------------------------------------------
__global__ __launch_bounds__(256) void gram_kernel(
    const _Float16* __restrict__ xbuf,  // [B,N,64]
    const float*    __restrict__ sq,    // [B,N]
    const float*    __restrict__ beta,  // [1]
    float*          __restrict__ out)   // [B,N,N]
{
    const int tid  = threadIdx.x;
    const int wid  = tid >> 6;
    const int lane = tid & 63;
    const int l15  = lane & 15;
    const int lg   = lane >> 4;
    const int b    = blockIdx.z;
    const int jb   = blockIdx.x * 512;
    const int rb   = blockIdx.y * 64;

    const _Float16* xb  = xbuf + (size_t)b * NN * PC;
    const float*    sqb = sq + (size_t)b * NN;

    const float bs   = -beta[0] * 1.44269504088896f;  // exp(-b*d2)=exp2(bs*d2)
    const float m2bs = -2.f * bs;

    // B fragments for this wave's 128 j (held across all 4 slices).
    f16x8 bf[8][2];
    float tj[8];
#pragma unroll
    for (int jtf = 0; jtf < 8; ++jtf) {
        const int j = jb + wid * 128 + jtf * 16 + l15;
#pragma unroll
        for (int ks = 0; ks < 2; ++ks)
            bf[jtf][ks] = *reinterpret_cast<const f16x8*>(
                xb + (size_t)j * PC + ks * 32 + lg * 8);
        tj[jtf] = bs * sqb[j];
    }

    __shared__ float lds[16][516];

    for (int sl = 0; sl < 4; ++sl) {
        const int ibase = rb + sl * 16;

        const f16x8 af0 = *reinterpret_cast<const f16x8*>(
            xb + (size_t)(ibase + l15) * PC + lg * 8);
        const f16x8 af1 = *reinterpret_cast<const f16x8*>(
            xb + (size_t)(ibase + l15) * PC + 32 + lg * 8);

        f32x4 acc[8];
#pragma unroll
        for (int jtf = 0; jtf < 8; ++jtf) {
            f32x4 z = {0.f, 0.f, 0.f, 0.f};
            acc[jtf] = __builtin_amdgcn_mfma_f32_16x16x32_f16(af0, bf[jtf][0], z, 0, 0, 0);
        }
#pragma unroll
        for (int jtf = 0; jtf < 8; ++jtf)
            acc[jtf] = __builtin_amdgcn_mfma_f32_16x16x32_f16(af1, bf[jtf][1], acc[jtf], 0, 0, 0);

        float ti[4];
#pragma unroll
        for (int r = 0; r < 4; ++r) ti[r] = bs * sqb[ibase + lg * 4 + r];

        if (sl) __syncthreads();   // previous slice's copy-out must be done

#pragma unroll
        for (int jtf = 0; jtf < 8; ++jtf) {
#pragma unroll
            for (int r = 0; r < 4; ++r) {
                float arg = fminf(fmaf(m2bs, acc[jtf][r], ti[r] + tj[jtf]), 0.f);
                lds[lg * 4 + r][wid * 128 + jtf * 16 + l15] =
                    __builtin_amdgcn_exp2f(arg);
            }
        }
        __syncthreads();

        // copy-out: 16 rows x 512 cols; each wave-instr = 1 KB contiguous.
#pragma unroll
        for (int rr = 0; rr < 4; ++rr) {
            const int row = rr * 4 + wid;
            float* orow = out + ((size_t)(b * NN + ibase + row)) * NN + jb;
#pragma unroll
            for (int c2 = 0; c2 < 2; ++c2) {
                const int col = c2 * 256 + lane * 4;
                *reinterpret_cast<f32x4*>(orow + col) =
                    *reinterpret_cast<const f32x4*>(&lds[row][col]);
            }
        }
    }
}

extern "C" void kernel_launch(void* const* d_in, const int* in_sizes, int n_in,
                              void* d_out, int out_size, void* d_ws, size_t ws_size,
                              hipStream_t stream) {
    const float* pos_bot = (const float*)d_in[0];
    const float* corr    = (const float*)d_in[1];
    const float* Wp      = (const float*)d_in[2];
    const float* bp      = (const float*)d_in[3];
    const float* Wv      = (const float*)d_in[4];
    const float* bv      = (const float*)d_in[5];
    const float* beta    = (const float*)d_in[6];

    float* out = (float*)d_out;                       // kernel [B,N,N]
    float* eqF = out + (size_t)BB * NN * NN;          // equation_F [B,N,128]

    _Float16* xbuf = (_Float16*)d_ws;                 // 2 MB
    float* sq = (float*)((char*)d_ws + (size_t)BB * NN * PC * sizeof(_Float16));

    proj_kernel<<<dim3(NN / 16, 2 * BB), 256, 0, stream>>>(
        pos_bot, corr, Wp, bp, Wv, bv, xbuf, sq, eqF);

    gram_kernel<<<dim3(NN / 512, NN / 64, BB), 256, 0, stream>>>(
        xbuf, sq, beta, out);
}

// Round 6
// 70.617 us; speedup vs baseline: 1.1322x; 1.0203x over previous
//
#include <hip/hip_runtime.h>
#include <hip/hip_bf16.h>

typedef _Float16 f16x8 __attribute__((ext_vector_type(8)));
typedef _Float16 f16x4 __attribute__((ext_vector_type(4)));
typedef float    f32x4 __attribute__((ext_vector_type(4)));

constexpr int BB = 4;
constexpr int CH = 128;
constexpr int PC = 64;
constexpr int NN = 4096;

// ---------------------------------------------------------------------------
// proj: one launch, grid (N/16, 2*B). role = y>>2 (0: pos-projection + sq,
// 1: value-projection). Identical to round 5 except eqF uses nontemporal
// stores (write-once, never re-read on device).
// ---------------------------------------------------------------------------
__global__ __launch_bounds__(256) void proj_kernel(
    const float* __restrict__ pos_bot,  // [B,64,N]
    const float* __restrict__ corr,     // [B,128,N]
    const float* __restrict__ Wp,       // [64,64]
    const float* __restrict__ bp,       // [64]
    const float* __restrict__ Wv,       // [128,128]
    const float* __restrict__ bv,       // [128]
    _Float16* __restrict__ xbuf,        // [B,N,64]  (re-read by gram: cached)
    float*    __restrict__ sq,          // [B,N]     (re-read by gram: cached)
    float*    __restrict__ eqF)         // [B,N,128] (write-once: nt)
{
    const int tid  = threadIdx.x;
    const int wid  = tid >> 6;
    const int lane = tid & 63;
    const int l15  = lane & 15;
    const int lg   = lane >> 4;
    const int b    = blockIdx.y & 3;
    const int n    = blockIdx.x * 16 + l15;

    if ((blockIdx.y >> 2) == 0) {
        // ---- pos projection: x~ = f16(Wp @ pos_bot + bp), sq = ||x~||^2 ----
        const int mt = wid;
        f16x8 wf[2], pb[2];
#pragma unroll
        for (int ks = 0; ks < 2; ++ks) {
            const float* wp = Wp + (mt * 16 + l15) * PC + ks * 32 + lg * 8;
            f32x4 w0 = *reinterpret_cast<const f32x4*>(wp);
            f32x4 w1 = *reinterpret_cast<const f32x4*>(wp + 4);
            f16x8 f;
#pragma unroll
            for (int e = 0; e < 4; ++e) { f[e] = (_Float16)w0[e]; f[e + 4] = (_Float16)w1[e]; }
            wf[ks] = f;
            f16x8 g;
#pragma unroll
            for (int e = 0; e < 8; ++e) {
                const int c = ks * 32 + lg * 8 + e;
                g[e] = (_Float16)pos_bot[((size_t)(b * PC + c)) * NN + n];
            }
            pb[ks] = g;
        }

        f32x4 acc = {0.f, 0.f, 0.f, 0.f};
        acc = __builtin_amdgcn_mfma_f32_16x16x32_f16(wf[0], pb[0], acc, 0, 0, 0);
        acc = __builtin_amdgcn_mfma_f32_16x16x32_f16(wf[1], pb[1], acc, 0, 0, 0);

        float partial = 0.f;
        f16x4 h4;
#pragma unroll
        for (int r = 0; r < 4; ++r) {
            const int o = mt * 16 + lg * 4 + r;
            const float v = acc[r] + bp[o];
            const _Float16 h = (_Float16)v;
            h4[r] = h;
            const float hf = (float)h;
            partial = fmaf(hf, hf, partial);
        }
        *reinterpret_cast<f16x4*>(xbuf + ((size_t)(b * NN + n)) * PC + mt * 16 + lg * 4) = h4;

        partial += __shfl_xor(partial, 16);
        partial += __shfl_xor(partial, 32);
        __shared__ float psum[4][16];
        if (lane < 16) psum[wid][l15] = partial;
        __syncthreads();
        if (tid < 16)
            sq[b * NN + blockIdx.x * 16 + tid] =
                psum[0][tid] + psum[1][tid] + psum[2][tid] + psum[3][tid];
        return;
    }

    // ---- value projection: eqF = Wv @ corr + bv ----
    f16x8 cb[4];
#pragma unroll
    for (int ks = 0; ks < 4; ++ks) {
        f16x8 g;
#pragma unroll
        for (int e = 0; e < 8; ++e) {
            const int c = ks * 32 + lg * 8 + e;
            g[e] = (_Float16)corr[((size_t)(b * CH + c)) * NN + n];
        }
        cb[ks] = g;
    }
#pragma unroll
    for (int half = 0; half < 2; ++half) {
        const int ot = wid + half * 4;   // 0..7
        f32x4 acc = {0.f, 0.f, 0.f, 0.f};
#pragma unroll
        for (int ks = 0; ks < 4; ++ks) {
            const float* wv = Wv + (ot * 16 + l15) * CH + ks * 32 + lg * 8;
            f32x4 w0 = *reinterpret_cast<const f32x4*>(wv);
            f32x4 w1 = *reinterpret_cast<const f32x4*>(wv + 4);
            f16x8 f;
#pragma unroll
            for (int e = 0; e < 4; ++e) { f[e] = (_Float16)w0[e]; f[e + 4] = (_Float16)w1[e]; }
            acc = __builtin_amdgcn_mfma_f32_16x16x32_f16(f, cb[ks], acc, 0, 0, 0);
        }
        f32x4 o4;
#pragma unroll
        for (int r = 0; r < 4; ++r) o4[r] = acc[r] + bv[ot * 16 + lg * 4 + r];
        __builtin_nontemporal_store(
            o4, reinterpret_cast<f32x4*>(eqF + ((size_t)(b * NN + n)) * CH + ot * 16 + lg * 4));
    }
}

// ---------------------------------------------------------------------------
// gram: identical to round 5 (MFMA -> exp2 -> LDS transpose -> contiguous
// copy-out) except the output stores are NONTEMPORAL: out is write-once and
// 268 MB sweeps L2 ~8x; nt keeps the stream out of the cache so xbuf/sq stay
// resident and the write path doesn't pay allocate+evict.
// ---------------------------------------------------------------------------
__global__ __launch_bounds__(256) void gram_kernel(
    const _Float16* __restrict__ xbuf,  // [B,N,64]
    const float*    __restrict__ sq,    // [B,N]
    const float*    __restrict__ beta,  // [1]
    float*          __restrict__ out)   // [B,N,N]
{
    const int tid  = threadIdx.x;
    const int wid  = tid >> 6;
    const int lane = tid & 63;
    const int l15  = lane & 15;
    const int lg   = lane >> 4;
    const int b    = blockIdx.z;
    const int jb   = blockIdx.x * 512;
    const int rb   = blockIdx.y * 64;

    const _Float16* xb  = xbuf + (size_t)b * NN * PC;
    const float*    sqb = sq + (size_t)b * NN;

    const float bs   = -beta[0] * 1.44269504088896f;  // exp(-b*d2)=exp2(bs*d2)
    const float m2bs = -2.f * bs;

    // B fragments for this wave's 128 j (held across all 4 slices).
    f16x8 bf[8][2];
    float tj[8];
#pragma unroll
    for (int jtf = 0; jtf < 8; ++jtf) {
        const int j = jb + wid * 128 + jtf * 16 + l15;
#pragma unroll
        for (int ks = 0; ks < 2; ++ks)
            bf[jtf][ks] = *reinterpret_cast<const f16x8*>(
                xb + (size_t)j * PC + ks * 32 + lg * 8);
        tj[jtf] = bs * sqb[j];
    }

    __shared__ float lds[16][516];

    for (int sl = 0; sl < 4; ++sl) {
        const int ibase = rb + sl * 16;

        const f16x8 af0 = *reinterpret_cast<const f16x8*>(
            xb + (size_t)(ibase + l15) * PC + lg * 8);
        const f16x8 af1 = *reinterpret_cast<const f16x8*>(
            xb + (size_t)(ibase + l15) * PC + 32 + lg * 8);

        f32x4 acc[8];
#pragma unroll
        for (int jtf = 0; jtf < 8; ++jtf) {
            f32x4 z = {0.f, 0.f, 0.f, 0.f};
            acc[jtf] = __builtin_amdgcn_mfma_f32_16x16x32_f16(af0, bf[jtf][0], z, 0, 0, 0);
        }
#pragma unroll
        for (int jtf = 0; jtf < 8; ++jtf)
            acc[jtf] = __builtin_amdgcn_mfma_f32_16x16x32_f16(af1, bf[jtf][1], acc[jtf], 0, 0, 0);

        float ti[4];
#pragma unroll
        for (int r = 0; r < 4; ++r) ti[r] = bs * sqb[ibase + lg * 4 + r];

        if (sl) __syncthreads();   // previous slice's copy-out must be done

#pragma unroll
        for (int jtf = 0; jtf < 8; ++jtf) {
#pragma unroll
            for (int r = 0; r < 4; ++r) {
                float arg = fminf(fmaf(m2bs, acc[jtf][r], ti[r] + tj[jtf]), 0.f);
                lds[lg * 4 + r][wid * 128 + jtf * 16 + l15] =
                    __builtin_amdgcn_exp2f(arg);
            }
        }
        __syncthreads();

        // copy-out: 16 rows x 512 cols; each wave-instr = 1 KB contiguous, nt.
#pragma unroll
        for (int rr = 0; rr < 4; ++rr) {
            const int row = rr * 4 + wid;
            float* orow = out + ((size_t)(b * NN + ibase + row)) * NN + jb;
#pragma unroll
            for (int c2 = 0; c2 < 2; ++c2) {
                const int col = c2 * 256 + lane * 4;
                __builtin_nontemporal_store(
                    *reinterpret_cast<const f32x4*>(&lds[row][col]),
                    reinterpret_cast<f32x4*>(orow + col));
            }
        }
    }
}

extern "C" void kernel_launch(void* const* d_in, const int* in_sizes, int n_in,
                              void* d_out, int out_size, void* d_ws, size_t ws_size,
                              hipStream_t stream) {
    const float* pos_bot = (const float*)d_in[0];
    const float* corr    = (const float*)d_in[1];
    const float* Wp      = (const float*)d_in[2];
    const float* bp      = (const float*)d_in[3];
    const float* Wv      = (const float*)d_in[4];
    const float* bv      = (const float*)d_in[5];
    const float* beta    = (const float*)d_in[6];

    float* out = (float*)d_out;                       // kernel [B,N,N]
    float* eqF = out + (size_t)BB * NN * NN;          // equation_F [B,N,128]

    _Float16* xbuf = (_Float16*)d_ws;                 // 2 MB
    float* sq = (float*)((char*)d_ws + (size_t)BB * NN * PC * sizeof(_Float16));

    proj_kernel<<<dim3(NN / 16, 2 * BB), 256, 0, stream>>>(
        pos_bot, corr, Wp, bp, Wv, bv, xbuf, sq, eqF);

    gram_kernel<<<dim3(NN / 512, NN / 64, BB), 256, 0, stream>>>(
        xbuf, sq, beta, out);
}